// Round 1
// baseline (8576.087 us; speedup 1.0000x reference)
//
#include <hip/hip_runtime.h>

#define D_IN 128
#define HID 256

// ---------------- degree / norm ----------------

__global__ void init_deg_kernel(float* __restrict__ deg, int n) {
  int i = blockIdx.x * 256 + threadIdx.x;
  if (i < n) deg[i] = 1.0f;  // self-loop contributes 1 to every node's degree
}

__global__ void count_deg_kernel(const int* __restrict__ dst, float* __restrict__ deg, int E) {
  int e = blockIdx.x * 256 + threadIdx.x;
  if (e < E) atomicAdd(&deg[dst[e]], 1.0f);
}

__global__ void make_dinv_kernel(float* __restrict__ deg, int n) {
  int i = blockIdx.x * 256 + threadIdx.x;
  if (i < n) deg[i] = rsqrtf(deg[i]);  // deg >= 1 always (self-loops)
}

// ---------------- fp32 GEMM: H[n,COLS] = X[n,K] @ W[K,COLS] ----------------
// Block: COLS threads (one output column each), 32 rows per block.
// x-tile stored transposed (xsT[k][r]) with pad 36 so reads are float4-able
// and staging writes are only 4-way bank-conflicted (negligible: 1024 writes).

template<int COLS>
__launch_bounds__(COLS)
__global__ void gemm_kernel(const float* __restrict__ X, const float* __restrict__ W,
                            float* __restrict__ H, int n, int K) {
  __shared__ float xsT[32][36];
  __shared__ float ws[32][COLS];
  const int col = threadIdx.x;
  const int row0 = blockIdx.x * 32;

  float acc[32];
#pragma unroll
  for (int r = 0; r < 32; ++r) acc[r] = 0.f;

  for (int kt = 0; kt < K; kt += 32) {
    // stage X tile (32 rows x 32 k), transposed
    for (int i = threadIdx.x; i < 32 * 32; i += COLS) {
      int r = i >> 5, k = i & 31;
      int row = row0 + r;
      xsT[k][r] = (row < n) ? X[(size_t)row * K + kt + k] : 0.f;
    }
    // stage W tile (32 k x COLS), coalesced
#pragma unroll 4
    for (int k = 0; k < 32; ++k) ws[k][col] = W[(size_t)(kt + k) * COLS + col];
    __syncthreads();

#pragma unroll 4
    for (int k = 0; k < 32; ++k) {
      float wv = ws[k][col];
      const float4* xr = (const float4*)(&xsT[k][0]);
#pragma unroll
      for (int j = 0; j < 8; ++j) {
        float4 xv = xr[j];
        acc[4 * j + 0] = fmaf(xv.x, wv, acc[4 * j + 0]);
        acc[4 * j + 1] = fmaf(xv.y, wv, acc[4 * j + 1]);
        acc[4 * j + 2] = fmaf(xv.z, wv, acc[4 * j + 2]);
        acc[4 * j + 3] = fmaf(xv.w, wv, acc[4 * j + 3]);
      }
    }
    __syncthreads();
  }

#pragma unroll
  for (int r = 0; r < 32; ++r) {
    int row = row0 + r;
    if (row < n) H[(size_t)row * COLS + col] = acc[r];
  }
}

// ---------------- edge aggregation (scatter-add with sym-norm) ----------------
// Edges e < E come from the edge list; e in [E, E+n) are self-loops.
// D/4 threads per edge, float4 gather from H[src], 4 scalar atomics to OUT[dst].

template<int D>
__global__ void aggregate_kernel(const float* __restrict__ H,
                                 const int* __restrict__ srcArr,
                                 const int* __restrict__ dstArr,
                                 const float* __restrict__ dinv,
                                 float* __restrict__ OUT, int E, int n) {
  constexpr int TPE = D / 4;        // threads per edge
  constexpr int EPB = 256 / TPE;    // edges per block
  const int lane = threadIdx.x % TPE;
  const int slot = threadIdx.x / TPE;
  const int e = blockIdx.x * EPB + slot;
  const int total = E + n;
  if (e >= total) return;

  int s, d;
  float w;
  if (e < E) {
    s = srcArr[e];
    d = dstArr[e];
    w = dinv[s] * dinv[d];
  } else {
    s = d = e - E;
    float dv = dinv[s];
    w = dv * dv;
  }

  const float4* hp = (const float4*)(H + (size_t)s * D);
  float4 v = hp[lane];
  float* op = OUT + (size_t)d * D + lane * 4;
  atomicAdd(op + 0, v.x * w);
  atomicAdd(op + 1, v.y * w);
  atomicAdd(op + 2, v.z * w);
  atomicAdd(op + 3, v.w * w);
}

// ---------------- elementwise ----------------

__global__ void bias_relu_kernel(float* __restrict__ A, const float* __restrict__ b) {
  // grid = n blocks of HID threads; col == threadIdx.x
  size_t i = (size_t)blockIdx.x * HID + threadIdx.x;
  float v = A[i] + b[threadIdx.x];
  A[i] = v > 0.f ? v : 0.f;
}

__global__ void init_out_kernel(float* __restrict__ out, const float* __restrict__ x,
                                const float* __restrict__ b) {
  // grid = n blocks of D_OUT(=128) threads; out = skip(x) + bias2, aggregation adds on top
  size_t i = (size_t)blockIdx.x * D_IN + threadIdx.x;
  out[i] = x[i] + b[threadIdx.x];
}

// ---------------- launch ----------------

extern "C" void kernel_launch(void* const* d_in, const int* in_sizes, int n_in,
                              void* d_out, int out_size, void* d_ws, size_t ws_size,
                              hipStream_t stream) {
  const float* x  = (const float*)d_in[0];
  const int*   ei = (const int*)d_in[1];
  const float* W1 = (const float*)d_in[2];
  const float* b1 = (const float*)d_in[3];
  const float* W2 = (const float*)d_in[4];
  const float* b2 = (const float*)d_in[5];
  float* out = (float*)d_out;

  const int N = in_sizes[0] / D_IN;
  const int E = in_sizes[1] / 2;
  const int* srcA = ei;       // edge_index[0]
  const int* dstA = ei + E;   // edge_index[1]

  // workspace layout: dinv [N] | hbuf [N*HID] (reused as h2 [N*D_IN]) | agg1 [N*HID]
  char* ws = (char*)d_ws;
  float* dinv = (float*)ws;
  size_t off_h = 256 * 1024;
  float* hbuf = (float*)(ws + off_h);
  size_t sz_h = (size_t)N * HID * sizeof(float);
  size_t off_agg = (off_h + sz_h + 255) & ~(size_t)255;
  float* agg1 = (float*)(ws + off_agg);

  // 1) symmetric norm: dinv = rsqrt(1 + in-degree)
  init_deg_kernel<<<(N + 255) / 256, 256, 0, stream>>>(dinv, N);
  count_deg_kernel<<<(E + 255) / 256, 256, 0, stream>>>(dstA, dinv, E);
  make_dinv_kernel<<<(N + 255) / 256, 256, 0, stream>>>(dinv, N);

  // 2) h1 = x @ W1
  gemm_kernel<HID><<<(N + 31) / 32, HID, 0, stream>>>(x, W1, hbuf, N, D_IN);

  // 3) agg1 = scatter-add(norm * h1[src] -> dst), then +b1, relu
  hipMemsetAsync(agg1, 0, (size_t)N * HID * sizeof(float), stream);
  {
    int total = E + N;
    aggregate_kernel<HID><<<(total + 3) / 4, 256, 0, stream>>>(hbuf, srcA, dstA, dinv, agg1, E, N);
  }
  bias_relu_kernel<<<N, HID, 0, stream>>>(agg1, b1);

  // 4) h2 = relu(agg1) @ W2  (reuse hbuf)
  gemm_kernel<D_IN><<<(N + 31) / 32, D_IN, 0, stream>>>(agg1, W2, hbuf, N, HID);

  // 5) out = x + b2 + scatter-add(norm * h2[src] -> dst)
  init_out_kernel<<<N, D_IN, 0, stream>>>(out, x, b2);
  {
    int total = E + N;
    aggregate_kernel<D_IN><<<(total + 7) / 8, 256, 0, stream>>>(hbuf, srcA, dstA, dinv, out, E, N);
  }
}

// Round 2
// 687.674 us; speedup vs baseline: 12.4711x; 12.4711x over previous
//
#include <hip/hip_runtime.h>

#define D_IN 128
#define HID 256

// ---------------- degree count (int) ----------------

__global__ void count_deg_kernel(const int* __restrict__ dst, int* __restrict__ cnt, int E) {
  int e = blockIdx.x * 256 + threadIdx.x;
  if (e < E) atomicAdd(&cnt[dst[e]], 1);
}

__global__ void make_dinv_kernel(const int* __restrict__ cnt, float* __restrict__ dinv, int n) {
  int i = blockIdx.x * 256 + threadIdx.x;
  if (i < n) dinv[i] = rsqrtf((float)(cnt[i] + 1));  // +1 = self-loop
}

// ---------------- single-block exclusive scan (N up to ~10^6) ----------------
// 1024 threads, shfl wave-scan + 16 wave-sums scanned by wave 0. ~49 chunks for N=50k.

__global__ __launch_bounds__(1024) void scan_kernel(const int* __restrict__ cnt,
                                                    int* __restrict__ row_start, int n) {
  __shared__ int wsums[16];
  __shared__ int s_carry;
  const int tid = threadIdx.x;
  const int lane = tid & 63;
  const int wid = tid >> 6;
  if (tid == 0) s_carry = 0;
  __syncthreads();
  for (int base = 0; base < n; base += 1024) {
    const int i = base + tid;
    const int orig = (i < n) ? cnt[i] : 0;
    int v = orig;
#pragma unroll
    for (int off = 1; off < 64; off <<= 1) {
      int t = __shfl_up(v, off);
      if (lane >= off) v += t;
    }
    if (lane == 63) wsums[wid] = v;
    __syncthreads();
    if (wid == 0) {
      int wv = (lane < 16) ? wsums[lane] : 0;
#pragma unroll
      for (int off = 1; off < 16; off <<= 1) {
        int t = __shfl_up(wv, off);
        if (lane >= off) wv += t;
      }
      if (lane < 16) wsums[lane] = wv;  // inclusive wave-sum scan
    }
    __syncthreads();
    const int wave_excl = wid ? wsums[wid - 1] : 0;
    const int excl = s_carry + wave_excl + (v - orig);
    if (i < n) row_start[i] = excl;
    const int total = wsums[15];
    __syncthreads();
    if (tid == 0) s_carry += total;
    __syncthreads();
  }
  if (tid == 0) row_start[n] = s_carry;
}

// ---------------- CSR scatter (edge -> slot under its dst row) ----------------

__global__ void scatter_kernel(const int* __restrict__ src, const int* __restrict__ dst,
                               const float* __restrict__ dinv,
                               const int* __restrict__ row_start, int* __restrict__ cursor,
                               int* __restrict__ csr_src, float* __restrict__ csr_w, int E) {
  int e = blockIdx.x * 256 + threadIdx.x;
  if (e >= E) return;
  int s = src[e], d = dst[e];
  int pos = row_start[d] + atomicAdd(&cursor[d], 1);
  csr_src[pos] = s;
  csr_w[pos] = dinv[s] * dinv[d];
}

// ---------------- CSR aggregation: OUT[d] = sum_j w_j * H[src_j] (+self +skip +bias) ----------------
// D=128 fixed. 32 lanes per node (float4 each), 8 nodes per 256-thread block. No atomics.

template<bool SKIP_BIAS>
__global__ __launch_bounds__(256) void agg_csr_kernel(const float* __restrict__ H,
                                                      const int* __restrict__ row_start,
                                                      const int* __restrict__ csr_src,
                                                      const float* __restrict__ csr_w,
                                                      const float* __restrict__ dinv,
                                                      const float* __restrict__ skip,
                                                      const float* __restrict__ bias,
                                                      float* __restrict__ OUT, int n) {
  const int lane = threadIdx.x & 31;
  const int node = blockIdx.x * 8 + (threadIdx.x >> 5);
  if (node >= n) return;

  const float dv = dinv[node];
  const float wself = dv * dv;
  float4 v = ((const float4*)(H + (size_t)node * D_IN))[lane];
  float4 acc;
  acc.x = v.x * wself; acc.y = v.y * wself; acc.z = v.z * wself; acc.w = v.w * wself;

  const int beg = row_start[node], end = row_start[node + 1];
  for (int j = beg; j < end; ++j) {
    const int s = csr_src[j];
    const float w = csr_w[j];
    float4 hv = ((const float4*)(H + (size_t)s * D_IN))[lane];
    acc.x = fmaf(hv.x, w, acc.x);
    acc.y = fmaf(hv.y, w, acc.y);
    acc.z = fmaf(hv.z, w, acc.z);
    acc.w = fmaf(hv.w, w, acc.w);
  }

  if (SKIP_BIAS) {
    float4 sk = ((const float4*)(skip + (size_t)node * D_IN))[lane];
    float4 bv = ((const float4*)bias)[lane];
    acc.x += sk.x + bv.x; acc.y += sk.y + bv.y; acc.z += sk.z + bv.z; acc.w += sk.w + bv.w;
  }
  ((float4*)(OUT + (size_t)node * D_IN))[lane] = acc;
}

// ---------------- fp32 GEMM: H[n,COLS] = X[n,K] @ W[K,COLS] (+bias, relu) ----------------

template<int COLS, bool BIAS_RELU>
__launch_bounds__(COLS)
__global__ void gemm_kernel(const float* __restrict__ X, const float* __restrict__ W,
                            const float* __restrict__ bias,
                            float* __restrict__ H, int n, int K) {
  __shared__ float xsT[32][36];
  __shared__ float ws[32][COLS];
  const int col = threadIdx.x;
  const int row0 = blockIdx.x * 32;

  float acc[32];
#pragma unroll
  for (int r = 0; r < 32; ++r) acc[r] = 0.f;

  for (int kt = 0; kt < K; kt += 32) {
    for (int i = threadIdx.x; i < 32 * 32; i += COLS) {
      int r = i >> 5, k = i & 31;
      int row = row0 + r;
      xsT[k][r] = (row < n) ? X[(size_t)row * K + kt + k] : 0.f;
    }
#pragma unroll 4
    for (int k = 0; k < 32; ++k) ws[k][col] = W[(size_t)(kt + k) * COLS + col];
    __syncthreads();

#pragma unroll 4
    for (int k = 0; k < 32; ++k) {
      float wv = ws[k][col];
      const float4* xr = (const float4*)(&xsT[k][0]);
#pragma unroll
      for (int j = 0; j < 8; ++j) {
        float4 xv = xr[j];
        acc[4 * j + 0] = fmaf(xv.x, wv, acc[4 * j + 0]);
        acc[4 * j + 1] = fmaf(xv.y, wv, acc[4 * j + 1]);
        acc[4 * j + 2] = fmaf(xv.z, wv, acc[4 * j + 2]);
        acc[4 * j + 3] = fmaf(xv.w, wv, acc[4 * j + 3]);
      }
    }
    __syncthreads();
  }

  const float bv = BIAS_RELU ? bias[col] : 0.f;
#pragma unroll
  for (int r = 0; r < 32; ++r) {
    int row = row0 + r;
    if (row < n) {
      float v = acc[r];
      if (BIAS_RELU) { v += bv; v = v > 0.f ? v : 0.f; }
      H[(size_t)row * COLS + col] = v;
    }
  }
}

// ---------------- launch ----------------

extern "C" void kernel_launch(void* const* d_in, const int* in_sizes, int n_in,
                              void* d_out, int out_size, void* d_ws, size_t ws_size,
                              hipStream_t stream) {
  const float* x  = (const float*)d_in[0];
  const int*   ei = (const int*)d_in[1];
  const float* W1 = (const float*)d_in[2];
  const float* b1 = (const float*)d_in[3];
  const float* W2 = (const float*)d_in[4];
  const float* b2 = (const float*)d_in[5];
  float* out = (float*)d_out;

  const int N = in_sizes[0] / D_IN;
  const int E = in_sizes[1] / 2;
  const int* srcA = ei;       // edge_index[0]
  const int* dstA = ei + E;   // edge_index[1]

  // ---- workspace layout (all 256B aligned) ----
  char* ws = (char*)d_ws;
  size_t off = 0;
  auto alloc = [&](size_t bytes) { void* p = ws + off; off = (off + bytes + 255) & ~(size_t)255; return p; };
  int*   cnt       = (int*)  alloc((size_t)N * 4);        // reused as cursor
  int*   row_start = (int*)  alloc((size_t)(N + 1) * 4);
  float* dinv      = (float*)alloc((size_t)N * 4);
  int*   csr_src   = (int*)  alloc((size_t)E * 4);
  float* csr_w     = (float*)alloc((size_t)E * 4);
  float* aggx      = (float*)alloc((size_t)N * D_IN * 4); // reused as t (h @ W2)
  float* h         = (float*)alloc((size_t)N * HID * 4);

  // 1) CSR build + sym-norm
  hipMemsetAsync(cnt, 0, (size_t)N * 4, stream);
  count_deg_kernel<<<(E + 255) / 256, 256, 0, stream>>>(dstA, cnt, E);
  make_dinv_kernel<<<(N + 255) / 256, 256, 0, stream>>>(cnt, dinv, N);
  scan_kernel<<<1, 1024, 0, stream>>>(cnt, row_start, N);
  hipMemsetAsync(cnt, 0, (size_t)N * 4, stream);  // cnt becomes cursor
  scatter_kernel<<<(E + 255) / 256, 256, 0, stream>>>(srcA, dstA, dinv, row_start, cnt,
                                                      csr_src, csr_w, E);

  // 2) aggx = Â x   (layer-1 aggregation done BEFORE the GEMM: D=128 not 256)
  agg_csr_kernel<false><<<(N + 7) / 8, 256, 0, stream>>>(x, row_start, csr_src, csr_w, dinv,
                                                         nullptr, nullptr, aggx, N);

  // 3) h = relu(aggx @ W1 + b1)
  gemm_kernel<HID, true><<<(N + 31) / 32, HID, 0, stream>>>(aggx, W1, b1, h, N, D_IN);

  // 4) t = h @ W2   (layer-2 GEMM done BEFORE the aggregation; reuse aggx buffer)
  gemm_kernel<D_IN, false><<<(N + 31) / 32, D_IN, 0, stream>>>(h, W2, nullptr, aggx, N, HID);

  // 5) out = Â t + x + b2
  agg_csr_kernel<true><<<(N + 7) / 8, 256, 0, stream>>>(aggx, row_start, csr_src, csr_w, dinv,
                                                        x, b2, out, N);
}

// Round 3
// 664.440 us; speedup vs baseline: 12.9072x; 1.0350x over previous
//
#include <hip/hip_runtime.h>

#define D_IN 128
#define HID 256

// ---------------- degree count ----------------

__global__ void count_deg_kernel(const int* __restrict__ dst, int* __restrict__ cnt, int E) {
  int e = blockIdx.x * 256 + threadIdx.x;
  if (e < E) atomicAdd(&cnt[dst[e]], 1);
}

// ---------------- hierarchical exclusive scan (1024 elems / block) ----------------
// scanA: per-element exclusive prefix within block + block sums; fuses dinv = rsqrt(deg+1).

__global__ __launch_bounds__(256) void scanA_kernel(const int* __restrict__ cnt,
                                                    float* __restrict__ dinv,
                                                    int* __restrict__ row_start,
                                                    int* __restrict__ blksum, int n) {
  __shared__ int wsums[4];
  const int tid = threadIdx.x;
  const int base = blockIdx.x * 1024 + tid * 4;
  int v0 = 0, v1 = 0, v2 = 0, v3 = 0;
  if (base + 3 < n) {
    int4 v = *(const int4*)(cnt + base);
    v0 = v.x; v1 = v.y; v2 = v.z; v3 = v.w;
  } else {
    if (base < n)     v0 = cnt[base];
    if (base + 1 < n) v1 = cnt[base + 1];
    if (base + 2 < n) v2 = cnt[base + 2];
    if (base + 3 < n) v3 = cnt[base + 3];
  }
  if (base < n)     dinv[base]     = rsqrtf((float)(v0 + 1));
  if (base + 1 < n) dinv[base + 1] = rsqrtf((float)(v1 + 1));
  if (base + 2 < n) dinv[base + 2] = rsqrtf((float)(v2 + 1));
  if (base + 3 < n) dinv[base + 3] = rsqrtf((float)(v3 + 1));

  const int s = v0 + v1 + v2 + v3;
  const int lane = tid & 63, wid = tid >> 6;
  int incl = s;
#pragma unroll
  for (int off = 1; off < 64; off <<= 1) {
    int t = __shfl_up(incl, off);
    if (lane >= off) incl += t;
  }
  if (lane == 63) wsums[wid] = incl;
  __syncthreads();
  int wexcl = 0;
  for (int w = 0; w < wid; ++w) wexcl += wsums[w];
  const int texcl = wexcl + incl - s;
  if (base < n)     row_start[base]     = texcl;
  if (base + 1 < n) row_start[base + 1] = texcl + v0;
  if (base + 2 < n) row_start[base + 2] = texcl + v0 + v1;
  if (base + 3 < n) row_start[base + 3] = texcl + v0 + v1 + v2;
  if (tid == 255) blksum[blockIdx.x] = wexcl + incl;
}

// scanB: single-wave exclusive scan of block sums (nb <= 64); blksum[nb] = total.
__global__ void scanB_kernel(int* __restrict__ blksum, int nb) {
  const int lane = threadIdx.x;
  int v = (lane < nb) ? blksum[lane] : 0;
  int incl = v;
#pragma unroll
  for (int off = 1; off < 64; off <<= 1) {
    int t = __shfl_up(incl, off);
    if (lane >= off) incl += t;
  }
  if (lane < nb) blksum[lane] = incl - v;
  if (lane == 63) blksum[nb] = incl;
}

// scanC: add block offsets; write row_start[n].
__global__ __launch_bounds__(256) void scanC_kernel(int* __restrict__ row_start,
                                                    const int* __restrict__ blksum,
                                                    int n, int nb) {
  const int base = blockIdx.x * 1024 + threadIdx.x * 4;
  const int off = blksum[blockIdx.x];
  if (blockIdx.x > 0) {
#pragma unroll
    for (int j = 0; j < 4; ++j)
      if (base + j < n) row_start[base + j] += off;
  }
  if (blockIdx.x == 0 && threadIdx.x == 0) row_start[n] = blksum[nb];
}

// ---------------- CSR scatter: packed {src, w} per edge ----------------

__global__ void scatter_kernel(const int* __restrict__ src, const int* __restrict__ dst,
                               const float* __restrict__ dinv,
                               const int* __restrict__ row_start, int* __restrict__ cursor,
                               int2* __restrict__ csr, int E) {
  int e = blockIdx.x * 256 + threadIdx.x;
  if (e >= E) return;
  int s = src[e], d = dst[e];
  int pos = row_start[d] + atomicAdd(&cursor[d], 1);
  csr[pos] = make_int2(s, __float_as_int(dinv[s] * dinv[d]));
}

// ---------------- CSR aggregation (D=128), unroll-4, no atomics ----------------

template<bool SKIP_BIAS>
__global__ __launch_bounds__(256) void agg_csr_kernel(const float* __restrict__ H,
                                                      const int* __restrict__ row_start,
                                                      const int2* __restrict__ csr,
                                                      const float* __restrict__ dinv,
                                                      const float* __restrict__ skip,
                                                      const float* __restrict__ bias,
                                                      float* __restrict__ OUT, int n) {
  const int lane = threadIdx.x & 31;
  const int node = blockIdx.x * 8 + (threadIdx.x >> 5);
  if (node >= n) return;

  const float dv = dinv[node];
  const float wself = dv * dv;
  float4 sv = ((const float4*)(H + (size_t)node * D_IN))[lane];
  float4 a0, a1, a2, a3;
  a0.x = sv.x * wself; a0.y = sv.y * wself; a0.z = sv.z * wself; a0.w = sv.w * wself;
  a1 = make_float4(0.f, 0.f, 0.f, 0.f);
  a2 = a1; a3 = a1;

  int j = row_start[node];
  const int end = row_start[node + 1];
  for (; j + 4 <= end; j += 4) {
    int2 e0 = csr[j], e1 = csr[j + 1], e2 = csr[j + 2], e3 = csr[j + 3];
    float4 h0 = ((const float4*)(H + (size_t)e0.x * D_IN))[lane];
    float4 h1 = ((const float4*)(H + (size_t)e1.x * D_IN))[lane];
    float4 h2 = ((const float4*)(H + (size_t)e2.x * D_IN))[lane];
    float4 h3 = ((const float4*)(H + (size_t)e3.x * D_IN))[lane];
    float w0 = __int_as_float(e0.y), w1 = __int_as_float(e1.y);
    float w2 = __int_as_float(e2.y), w3 = __int_as_float(e3.y);
    a0.x = fmaf(h0.x, w0, a0.x); a0.y = fmaf(h0.y, w0, a0.y); a0.z = fmaf(h0.z, w0, a0.z); a0.w = fmaf(h0.w, w0, a0.w);
    a1.x = fmaf(h1.x, w1, a1.x); a1.y = fmaf(h1.y, w1, a1.y); a1.z = fmaf(h1.z, w1, a1.z); a1.w = fmaf(h1.w, w1, a1.w);
    a2.x = fmaf(h2.x, w2, a2.x); a2.y = fmaf(h2.y, w2, a2.y); a2.z = fmaf(h2.z, w2, a2.z); a2.w = fmaf(h2.w, w2, a2.w);
    a3.x = fmaf(h3.x, w3, a3.x); a3.y = fmaf(h3.y, w3, a3.y); a3.z = fmaf(h3.z, w3, a3.z); a3.w = fmaf(h3.w, w3, a3.w);
  }
  for (; j < end; ++j) {
    int2 e0 = csr[j];
    float4 h0 = ((const float4*)(H + (size_t)e0.x * D_IN))[lane];
    float w0 = __int_as_float(e0.y);
    a0.x = fmaf(h0.x, w0, a0.x); a0.y = fmaf(h0.y, w0, a0.y); a0.z = fmaf(h0.z, w0, a0.z); a0.w = fmaf(h0.w, w0, a0.w);
  }
  float4 acc;
  acc.x = (a0.x + a1.x) + (a2.x + a3.x);
  acc.y = (a0.y + a1.y) + (a2.y + a3.y);
  acc.z = (a0.z + a1.z) + (a2.z + a3.z);
  acc.w = (a0.w + a1.w) + (a2.w + a3.w);

  if (SKIP_BIAS) {
    float4 sk = ((const float4*)(skip + (size_t)node * D_IN))[lane];
    float4 bv = ((const float4*)bias)[lane];
    acc.x += sk.x + bv.x; acc.y += sk.y + bv.y; acc.z += sk.z + bv.z; acc.w += sk.w + bv.w;
  }
  ((float4*)(OUT + (size_t)node * D_IN))[lane] = acc;
}

// ---------------- fp32 GEMM: H[n,COLS] = X[n,K] @ W[K,COLS] (+bias, relu) ----------------
// 64x128 tile, 256 threads, 8 rows x 4 cols per thread. A transposed in LDS (pad 68 keeps
// 16B alignment of the [k][ty*8] reads; staging writes 4-way conflicted — negligible count).

template<int COLS, bool BIAS_RELU>
__global__ __launch_bounds__(256) void gemm_kernel(const float* __restrict__ X,
                                                   const float* __restrict__ W,
                                                   const float* __restrict__ bias,
                                                   float* __restrict__ H, int n, int K) {
  __shared__ float asT[32][68];
  __shared__ float bs[32][128];
  const int tid = threadIdx.x;
  const int tx = tid & 31;   // 4-col group
  const int ty = tid >> 5;   // 8-row group
  const int row0 = blockIdx.x * 64;
  const int col0 = blockIdx.y * 128;

  float acc[8][4];
#pragma unroll
  for (int r = 0; r < 8; ++r)
#pragma unroll
    for (int c = 0; c < 4; ++c) acc[r][c] = 0.f;

  for (int kt = 0; kt < K; kt += 32) {
#pragma unroll
    for (int i = tid; i < 2048; i += 256) {  // A tile: 64 rows x 32 k
      int k = i & 31, r = i >> 5;
      int row = row0 + r;
      asT[k][r] = (row < n) ? X[(size_t)row * K + kt + k] : 0.f;
    }
#pragma unroll
    for (int i = tid; i < 4096; i += 256) {  // B tile: 32 k x 128 c
      int c = i & 127, k = i >> 7;
      bs[k][c] = W[(size_t)(kt + k) * COLS + col0 + c];
    }
    __syncthreads();

#pragma unroll
    for (int k = 0; k < 32; ++k) {
      float4 av0 = *(const float4*)&asT[k][ty * 8];
      float4 av1 = *(const float4*)&asT[k][ty * 8 + 4];
      float4 bv = *(const float4*)&bs[k][tx * 4];
      float a[8] = {av0.x, av0.y, av0.z, av0.w, av1.x, av1.y, av1.z, av1.w};
      float b[4] = {bv.x, bv.y, bv.z, bv.w};
#pragma unroll
      for (int r = 0; r < 8; ++r)
#pragma unroll
        for (int c = 0; c < 4; ++c) acc[r][c] = fmaf(a[r], b[c], acc[r][c]);
    }
    __syncthreads();
  }

  float4 bvec = make_float4(0.f, 0.f, 0.f, 0.f);
  if (BIAS_RELU) bvec = *(const float4*)&bias[col0 + tx * 4];
#pragma unroll
  for (int r = 0; r < 8; ++r) {
    int row = row0 + ty * 8 + r;
    if (row < n) {
      float4 o = make_float4(acc[r][0], acc[r][1], acc[r][2], acc[r][3]);
      if (BIAS_RELU) {
        o.x += bvec.x; o.y += bvec.y; o.z += bvec.z; o.w += bvec.w;
        o.x = o.x > 0.f ? o.x : 0.f; o.y = o.y > 0.f ? o.y : 0.f;
        o.z = o.z > 0.f ? o.z : 0.f; o.w = o.w > 0.f ? o.w : 0.f;
      }
      *(float4*)&H[(size_t)row * COLS + col0 + tx * 4] = o;
    }
  }
}

// ---------------- launch ----------------

extern "C" void kernel_launch(void* const* d_in, const int* in_sizes, int n_in,
                              void* d_out, int out_size, void* d_ws, size_t ws_size,
                              hipStream_t stream) {
  const float* x  = (const float*)d_in[0];
  const int*   ei = (const int*)d_in[1];
  const float* W1 = (const float*)d_in[2];
  const float* b1 = (const float*)d_in[3];
  const float* W2 = (const float*)d_in[4];
  const float* b2 = (const float*)d_in[5];
  float* out = (float*)d_out;

  const int N = in_sizes[0] / D_IN;
  const int E = in_sizes[1] / 2;
  const int* srcA = ei;       // edge_index[0]
  const int* dstA = ei + E;   // edge_index[1]
  const int NB = (N + 1023) / 1024;  // scan blocks (<= 64 for N <= 65536)

  // ---- workspace layout (256B aligned) ----
  char* ws = (char*)d_ws;
  size_t off = 0;
  auto alloc = [&](size_t bytes) { void* p = ws + off; off = (off + bytes + 255) & ~(size_t)255; return p; };
  int*   cnt       = (int*)  alloc((size_t)N * 4);        // reused as cursor
  int*   row_start = (int*)  alloc((size_t)(N + 1) * 4);
  float* dinv      = (float*)alloc((size_t)N * 4);
  int*   blksum    = (int*)  alloc((size_t)(NB + 1) * 4);
  int2*  csr       = (int2*) alloc((size_t)E * 8);
  float* aggx      = (float*)alloc((size_t)N * D_IN * 4); // reused as t = h @ W2
  float* h         = (float*)alloc((size_t)N * HID * 4);

  // 1) CSR build + sym-norm
  hipMemsetAsync(cnt, 0, (size_t)N * 4, stream);
  count_deg_kernel<<<(E + 255) / 256, 256, 0, stream>>>(dstA, cnt, E);
  scanA_kernel<<<NB, 256, 0, stream>>>(cnt, dinv, row_start, blksum, N);
  scanB_kernel<<<1, 64, 0, stream>>>(blksum, NB);
  scanC_kernel<<<NB, 256, 0, stream>>>(row_start, blksum, N, NB);
  hipMemsetAsync(cnt, 0, (size_t)N * 4, stream);  // cnt -> cursor
  scatter_kernel<<<(E + 255) / 256, 256, 0, stream>>>(srcA, dstA, dinv, row_start, cnt, csr, E);

  // 2) aggx = Â x
  agg_csr_kernel<false><<<(N + 7) / 8, 256, 0, stream>>>(x, row_start, csr, dinv,
                                                         nullptr, nullptr, aggx, N);
  // 3) h = relu(aggx @ W1 + b1)
  {
    dim3 g((N + 63) / 64, HID / 128);
    gemm_kernel<HID, true><<<g, 256, 0, stream>>>(aggx, W1, b1, h, N, D_IN);
  }
  // 4) t = h @ W2  (reuse aggx)
  {
    dim3 g((N + 63) / 64, D_IN / 128);
    gemm_kernel<D_IN, false><<<g, 256, 0, stream>>>(h, W2, nullptr, aggx, N, HID);
  }
  // 5) out = Â t + x + b2
  agg_csr_kernel<true><<<(N + 7) / 8, 256, 0, stream>>>(aggx, row_start, csr, dinv,
                                                        x, b2, out, N);
}

// Round 4
// 451.411 us; speedup vs baseline: 18.9984x; 1.4719x over previous
//
#include <hip/hip_runtime.h>

#define D_IN 128
#define HID 256

typedef __attribute__((ext_vector_type(8))) short short8;   // 8 bf16 (4 VGPRs) MFMA A/B frag
typedef __attribute__((ext_vector_type(4))) float floatx4;  // MFMA C/D frag

// fp32 -> bf16 (RNE), branch-free; inputs are finite
static __device__ __forceinline__ unsigned short f2b(float f) {
  unsigned u = __float_as_uint(f);
  unsigned r = (u + 0x7fffu + ((u >> 16) & 1u)) >> 16;
  return (unsigned short)r;
}

static __device__ __forceinline__ void unpack8(uint4 v, float* f) {
  f[0] = __uint_as_float(v.x << 16); f[1] = __uint_as_float(v.x & 0xffff0000u);
  f[2] = __uint_as_float(v.y << 16); f[3] = __uint_as_float(v.y & 0xffff0000u);
  f[4] = __uint_as_float(v.z << 16); f[5] = __uint_as_float(v.z & 0xffff0000u);
  f[6] = __uint_as_float(v.w << 16); f[7] = __uint_as_float(v.w & 0xffff0000u);
}

// ---------------- degree count ----------------

__global__ void count_deg_kernel(const int* __restrict__ dst, int* __restrict__ cnt, int E) {
  int e = blockIdx.x * 256 + threadIdx.x;
  if (e < E) atomicAdd(&cnt[dst[e]], 1);
}

// ---------------- hierarchical exclusive scan (1024 elems / block), dinv fused ----------------

__global__ __launch_bounds__(256) void scanA_kernel(const int* __restrict__ cnt,
                                                    float* __restrict__ dinv,
                                                    int* __restrict__ row_start,
                                                    int* __restrict__ blksum, int n) {
  __shared__ int wsums[4];
  const int tid = threadIdx.x;
  const int base = blockIdx.x * 1024 + tid * 4;
  int v0 = 0, v1 = 0, v2 = 0, v3 = 0;
  if (base + 3 < n) {
    int4 v = *(const int4*)(cnt + base);
    v0 = v.x; v1 = v.y; v2 = v.z; v3 = v.w;
  } else {
    if (base < n)     v0 = cnt[base];
    if (base + 1 < n) v1 = cnt[base + 1];
    if (base + 2 < n) v2 = cnt[base + 2];
    if (base + 3 < n) v3 = cnt[base + 3];
  }
  if (base < n)     dinv[base]     = rsqrtf((float)(v0 + 1));
  if (base + 1 < n) dinv[base + 1] = rsqrtf((float)(v1 + 1));
  if (base + 2 < n) dinv[base + 2] = rsqrtf((float)(v2 + 1));
  if (base + 3 < n) dinv[base + 3] = rsqrtf((float)(v3 + 1));

  const int s = v0 + v1 + v2 + v3;
  const int lane = tid & 63, wid = tid >> 6;
  int incl = s;
#pragma unroll
  for (int off = 1; off < 64; off <<= 1) {
    int t = __shfl_up(incl, off);
    if (lane >= off) incl += t;
  }
  if (lane == 63) wsums[wid] = incl;
  __syncthreads();
  int wexcl = 0;
  for (int w = 0; w < wid; ++w) wexcl += wsums[w];
  const int texcl = wexcl + incl - s;
  if (base < n)     row_start[base]     = texcl;
  if (base + 1 < n) row_start[base + 1] = texcl + v0;
  if (base + 2 < n) row_start[base + 2] = texcl + v0 + v1;
  if (base + 3 < n) row_start[base + 3] = texcl + v0 + v1 + v2;
  if (tid == 255) blksum[blockIdx.x] = wexcl + incl;
}

__global__ void scanB_kernel(int* __restrict__ blksum, int nb) {
  const int lane = threadIdx.x;
  int v = (lane < nb) ? blksum[lane] : 0;
  int incl = v;
#pragma unroll
  for (int off = 1; off < 64; off <<= 1) {
    int t = __shfl_up(incl, off);
    if (lane >= off) incl += t;
  }
  if (lane < nb) blksum[lane] = incl - v;
  if (lane == 63) blksum[nb] = incl;
}

__global__ __launch_bounds__(256) void scanC_kernel(int* __restrict__ row_start,
                                                    const int* __restrict__ blksum,
                                                    int n, int nb) {
  const int base = blockIdx.x * 1024 + threadIdx.x * 4;
  const int off = blksum[blockIdx.x];
  if (blockIdx.x > 0) {
#pragma unroll
    for (int j = 0; j < 4; ++j)
      if (base + j < n) row_start[base + j] += off;
  }
  if (blockIdx.x == 0 && threadIdx.x == 0) row_start[n] = blksum[nb];
}

// ---------------- CSR scatter: src only (w recomputed in agg) ----------------

__global__ void scatter_kernel(const int* __restrict__ src, const int* __restrict__ dst,
                               const int* __restrict__ row_start, int* __restrict__ cursor,
                               int* __restrict__ csr_src, int E) {
  int e = blockIdx.x * 256 + threadIdx.x;
  if (e >= E) return;
  int d = dst[e];
  int pos = row_start[d] + atomicAdd(&cursor[d], 1);
  csr_src[pos] = src[e];
}

// ---------------- conversions ----------------

__global__ void cvt_x_kernel(const float4* __restrict__ in, unsigned short* __restrict__ out,
                             int n4) {
  int i = blockIdx.x * 256 + threadIdx.x;
  if (i >= n4) return;
  float4 v = in[i];
  ushort4 o;
  o.x = f2b(v.x); o.y = f2b(v.y); o.z = f2b(v.z); o.w = f2b(v.w);
  *(ushort4*)(out + (size_t)i * 4) = o;
}

// W[K][N] fp32 -> Wt[N][K] bf16
__global__ void cvt_wt_kernel(const float* __restrict__ W, unsigned short* __restrict__ Wt,
                              int K, int N) {
  int e = blockIdx.x * 256 + threadIdx.x;
  if (e >= K * N) return;
  int k = e / N, n = e - k * N;
  Wt[(size_t)n * K + k] = f2b(W[e]);
}

// ---------------- MFMA bf16 GEMM: H[M][N_COLS] = A[M][K] @ Wt[N_COLS][K]^T ----------------
// 256 thr = 4 waves; block tile 64(M) x 64(N); each wave: 16 rows x 64 cols = 4 C-tiles.
// No LDS: A frag (16B) + 4 B frags (16B) per k-step straight from L2.
// Verified layouts (m89/m91/m120): A[m=lane&15][k=quad*8+j]; B[k=quad*8+j][n=lane&15];
// C/D: row=quad*4+reg, col=lane&15.

template<int N_COLS, int K, bool BIAS_RELU>
__global__ __launch_bounds__(256) void mfma_gemm_kernel(const unsigned short* __restrict__ A,
                                                        const unsigned short* __restrict__ Wt,
                                                        const float* __restrict__ bias,
                                                        unsigned short* __restrict__ H, int M) {
  const int tid = threadIdx.x;
  const int wave = tid >> 6;
  const int lane = tid & 63;
  const int quad = lane >> 4;
  const int l16 = lane & 15;
  const int row0 = blockIdx.x * 64 + wave * 16;
  const int col0 = blockIdx.y * 64;

  int arow = row0 + l16;
  if (arow >= M) arow = M - 1;  // tail: loads clamped, stores guarded
  const short8* ap = (const short8*)(A + (size_t)arow * K + quad * 8);
  const short8* bp = (const short8*)(Wt + (size_t)(col0 + l16) * K + quad * 8);
  constexpr int BSTEP = 2 * K;  // 16 rows of Wt in short8 units

  floatx4 acc0 = {0.f, 0.f, 0.f, 0.f}, acc1 = acc0, acc2 = acc0, acc3 = acc0;
#pragma unroll
  for (int kt = 0; kt < K / 32; ++kt) {
    short8 a  = ap[kt * 4];
    short8 b0 = bp[kt * 4];
    short8 b1 = bp[kt * 4 + BSTEP];
    short8 b2 = bp[kt * 4 + 2 * BSTEP];
    short8 b3 = bp[kt * 4 + 3 * BSTEP];
    acc0 = __builtin_amdgcn_mfma_f32_16x16x32_bf16(a, b0, acc0, 0, 0, 0);
    acc1 = __builtin_amdgcn_mfma_f32_16x16x32_bf16(a, b1, acc1, 0, 0, 0);
    acc2 = __builtin_amdgcn_mfma_f32_16x16x32_bf16(a, b2, acc2, 0, 0, 0);
    acc3 = __builtin_amdgcn_mfma_f32_16x16x32_bf16(a, b3, acc3, 0, 0, 0);
  }

  floatx4 accs[4] = {acc0, acc1, acc2, acc3};
#pragma unroll
  for (int t = 0; t < 4; ++t) {
    const int col = col0 + t * 16 + l16;
    const float bv = BIAS_RELU ? bias[col] : 0.f;
#pragma unroll
    for (int r = 0; r < 4; ++r) {
      const int row = row0 + quad * 4 + r;
      if (row < M) {
        float v = accs[t][r];
        if (BIAS_RELU) { v += bv; v = v > 0.f ? v : 0.f; }
        H[(size_t)row * N_COLS + col] = f2b(v);
      }
    }
  }
}

// ---------------- CSR aggregation over bf16 rows (D=128), fp32 accumulate ----------------
// 16 lanes/node (8 dims each, one uint4 = 8 bf16 per gather), 16 nodes / 256-thr block.

template<bool SKIP_BIAS>
__global__ __launch_bounds__(256) void agg_kernel(const uint4* __restrict__ Hq,  // bf16 [n][128]
                                                  const int* __restrict__ row_start,
                                                  const int* __restrict__ csr_src,
                                                  const float* __restrict__ dinv,
                                                  const float* __restrict__ skip,
                                                  const float* __restrict__ bias,
                                                  void* __restrict__ OUT, int n) {
  const int lane = threadIdx.x & 15;
  const int node = blockIdx.x * 16 + (threadIdx.x >> 4);
  if (node >= n) return;

  const float dv = dinv[node];
  float f[8], acc[8];
  uint4 sv = Hq[(size_t)node * 16 + lane];
  unpack8(sv, f);
  const float wself = dv * dv;
#pragma unroll
  for (int d = 0; d < 8; ++d) acc[d] = f[d] * wself;

  int j = row_start[node];
  const int end = row_start[node + 1];
  for (; j + 4 <= end; j += 4) {
    int s0 = csr_src[j], s1 = csr_src[j + 1], s2 = csr_src[j + 2], s3 = csr_src[j + 3];
    float w0 = dinv[s0] * dv, w1 = dinv[s1] * dv, w2 = dinv[s2] * dv, w3 = dinv[s3] * dv;
    uint4 v0 = Hq[(size_t)s0 * 16 + lane];
    uint4 v1 = Hq[(size_t)s1 * 16 + lane];
    uint4 v2 = Hq[(size_t)s2 * 16 + lane];
    uint4 v3 = Hq[(size_t)s3 * 16 + lane];
    float g[8];
    unpack8(v0, g);
#pragma unroll
    for (int d = 0; d < 8; ++d) acc[d] = fmaf(g[d], w0, acc[d]);
    unpack8(v1, g);
#pragma unroll
    for (int d = 0; d < 8; ++d) acc[d] = fmaf(g[d], w1, acc[d]);
    unpack8(v2, g);
#pragma unroll
    for (int d = 0; d < 8; ++d) acc[d] = fmaf(g[d], w2, acc[d]);
    unpack8(v3, g);
#pragma unroll
    for (int d = 0; d < 8; ++d) acc[d] = fmaf(g[d], w3, acc[d]);
  }
  for (; j < end; ++j) {
    int s0 = csr_src[j];
    float w0 = dinv[s0] * dv;
    uint4 v0 = Hq[(size_t)s0 * 16 + lane];
    float g[8];
    unpack8(v0, g);
#pragma unroll
    for (int d = 0; d < 8; ++d) acc[d] = fmaf(g[d], w0, acc[d]);
  }

  if (SKIP_BIAS) {
    // out fp32 = acc + skip + bias
    const float* sp = skip + (size_t)node * 128 + lane * 8;
    const float* bp = bias + lane * 8;
    float4 s0 = *(const float4*)sp, s1 = *(const float4*)(sp + 4);
    float4 b0 = *(const float4*)bp, b1 = *(const float4*)(bp + 4);
    float* op = (float*)OUT + (size_t)node * 128 + lane * 8;
    float4 o0 = make_float4(acc[0] + s0.x + b0.x, acc[1] + s0.y + b0.y,
                            acc[2] + s0.z + b0.z, acc[3] + s0.w + b0.w);
    float4 o1 = make_float4(acc[4] + s1.x + b1.x, acc[5] + s1.y + b1.y,
                            acc[6] + s1.z + b1.z, acc[7] + s1.w + b1.w);
    *(float4*)op = o0;
    *(float4*)(op + 4) = o1;
  } else {
    // out bf16 packed
    uint4 o;
    o.x = (unsigned)f2b(acc[0]) | ((unsigned)f2b(acc[1]) << 16);
    o.y = (unsigned)f2b(acc[2]) | ((unsigned)f2b(acc[3]) << 16);
    o.z = (unsigned)f2b(acc[4]) | ((unsigned)f2b(acc[5]) << 16);
    o.w = (unsigned)f2b(acc[6]) | ((unsigned)f2b(acc[7]) << 16);
    ((uint4*)OUT)[(size_t)node * 16 + lane] = o;
  }
}

// ---------------- launch ----------------

extern "C" void kernel_launch(void* const* d_in, const int* in_sizes, int n_in,
                              void* d_out, int out_size, void* d_ws, size_t ws_size,
                              hipStream_t stream) {
  const float* x  = (const float*)d_in[0];
  const int*   ei = (const int*)d_in[1];
  const float* W1 = (const float*)d_in[2];
  const float* b1 = (const float*)d_in[3];
  const float* W2 = (const float*)d_in[4];
  const float* b2 = (const float*)d_in[5];
  float* out = (float*)d_out;

  const int N = in_sizes[0] / D_IN;
  const int E = in_sizes[1] / 2;
  const int* srcA = ei;
  const int* dstA = ei + E;
  const int NB = (N + 1023) / 1024;  // <= 64 for N <= 65536

  // ---- workspace (256B aligned) ----
  char* ws = (char*)d_ws;
  size_t off = 0;
  auto alloc = [&](size_t bytes) { void* p = ws + off; off = (off + bytes + 255) & ~(size_t)255; return p; };
  int*            cnt       = (int*)           alloc((size_t)N * 4);  // reused as cursor
  int*            row_start = (int*)           alloc((size_t)(N + 1) * 4);
  float*          dinv      = (float*)         alloc((size_t)N * 4);
  int*            blksum    = (int*)           alloc((size_t)(NB + 1) * 4);
  int*            csr_src   = (int*)           alloc((size_t)E * 4);
  unsigned short* xb        = (unsigned short*)alloc((size_t)N * D_IN * 2);
  unsigned short* aggx      = (unsigned short*)alloc((size_t)N * D_IN * 2);
  unsigned short* h         = (unsigned short*)alloc((size_t)N * HID * 2);
  unsigned short* tb        = (unsigned short*)alloc((size_t)N * D_IN * 2);
  unsigned short* Wt1       = (unsigned short*)alloc((size_t)D_IN * HID * 2);
  unsigned short* Wt2       = (unsigned short*)alloc((size_t)D_IN * HID * 2);

  // 1) degree -> dinv + CSR row offsets
  hipMemsetAsync(cnt, 0, (size_t)N * 4, stream);
  count_deg_kernel<<<(E + 255) / 256, 256, 0, stream>>>(dstA, cnt, E);
  scanA_kernel<<<NB, 256, 0, stream>>>(cnt, dinv, row_start, blksum, N);
  scanB_kernel<<<1, 64, 0, stream>>>(blksum, NB);
  scanC_kernel<<<NB, 256, 0, stream>>>(row_start, blksum, N, NB);
  hipMemsetAsync(cnt, 0, (size_t)N * 4, stream);  // cnt -> cursor
  scatter_kernel<<<(E + 255) / 256, 256, 0, stream>>>(srcA, dstA, row_start, cnt, csr_src, E);

  // 2) conversions
  cvt_x_kernel<<<(N * D_IN / 4 + 255) / 256, 256, 0, stream>>>((const float4*)x, xb, N * D_IN / 4);
  cvt_wt_kernel<<<(D_IN * HID + 255) / 256, 256, 0, stream>>>(W1, Wt1, D_IN, HID);
  cvt_wt_kernel<<<(D_IN * HID + 255) / 256, 256, 0, stream>>>(W2, Wt2, HID, D_IN);

  // 3) aggx = Â x   (bf16 in, bf16 out)
  agg_kernel<false><<<(N + 15) / 16, 256, 0, stream>>>((const uint4*)xb, row_start, csr_src,
                                                       dinv, nullptr, nullptr, aggx, N);
  // 4) h = relu(aggx @ W1 + b1)  (MFMA, bf16 out)
  {
    dim3 g((N + 63) / 64, HID / 64);
    mfma_gemm_kernel<HID, D_IN, true><<<g, 256, 0, stream>>>(aggx, Wt1, b1, h, N);
  }
  // 5) t = h @ W2  (MFMA, bf16 out)
  {
    dim3 g((N + 63) / 64, D_IN / 64);
    mfma_gemm_kernel<D_IN, HID, false><<<g, 256, 0, stream>>>(h, Wt2, nullptr, tb, N);
  }
  // 6) out = Â t + x + b2  (fp32 out)
  agg_kernel<true><<<(N + 15) / 16, 256, 0, stream>>>((const uint4*)tb, row_start, csr_src,
                                                      dinv, x, b2, out, N);
}

// Round 5
// 357.935 us; speedup vs baseline: 23.9599x; 1.2612x over previous
//
#include <hip/hip_runtime.h>

#define D_IN 128
#define HID 256
#define BKT_SHIFT 9
#define BKT_SIZE 512     // nodes per bucket (N<=65536 -> nbkt<=128)
#define CHUNK 8192       // edges per block in binning kernels

typedef __attribute__((ext_vector_type(8))) short short8;   // 8 bf16 MFMA A/B frag
typedef __attribute__((ext_vector_type(4))) float floatx4;  // MFMA C/D frag

// fp32 -> bf16 (RNE), branch-free; inputs finite
static __device__ __forceinline__ unsigned short f2b(float f) {
  unsigned u = __float_as_uint(f);
  unsigned r = (u + 0x7fffu + ((u >> 16) & 1u)) >> 16;
  return (unsigned short)r;
}

static __device__ __forceinline__ void unpack8(uint4 v, float* f) {
  f[0] = __uint_as_float(v.x << 16); f[1] = __uint_as_float(v.x & 0xffff0000u);
  f[2] = __uint_as_float(v.y << 16); f[3] = __uint_as_float(v.y & 0xffff0000u);
  f[4] = __uint_as_float(v.z << 16); f[5] = __uint_as_float(v.z & 0xffff0000u);
  f[6] = __uint_as_float(v.w << 16); f[7] = __uint_as_float(v.w & 0xffff0000u);
}

// ================= CSR build: two-level binning sort =================

// P1a: global bucket histogram (LDS-staged)
__global__ __launch_bounds__(256) void bin_hist_kernel(const int* __restrict__ dst,
                                                       int* __restrict__ bkt_cnt,
                                                       int E, int nbkt) {
  __shared__ int hist[128];
  const int tid = threadIdx.x;
  if (tid < nbkt) hist[tid] = 0;
  __syncthreads();
  const int base = blockIdx.x * CHUNK;
  const int end = min(base + CHUNK, E);
  for (int e = base + tid; e < end; e += 256)
    atomicAdd(&hist[dst[e] >> BKT_SHIFT], 1);
  __syncthreads();
  if (tid < nbkt && hist[tid] > 0) atomicAdd(&bkt_cnt[tid], hist[tid]);
}

// P1b: exclusive scan of bucket counts (nbkt <= 128); init cursors
__global__ __launch_bounds__(128) void bkt_scan_kernel(const int* __restrict__ bkt_cnt,
                                                       int* __restrict__ bkt_start,
                                                       int* __restrict__ bkt_cursor,
                                                       int nbkt, int E) {
  __shared__ int w0tot;
  const int tid = threadIdx.x;
  const int lane = tid & 63, wid = tid >> 6;
  int v = (tid < nbkt) ? bkt_cnt[tid] : 0;
  int incl = v;
#pragma unroll
  for (int off = 1; off < 64; off <<= 1) {
    int t = __shfl_up(incl, off);
    if (lane >= off) incl += t;
  }
  if (wid == 0 && lane == 63) w0tot = incl;
  __syncthreads();
  int ex = incl - v + (wid ? w0tot : 0);
  if (tid < nbkt) { bkt_start[tid] = ex; bkt_cursor[tid] = ex; }
  if (tid == 0) bkt_start[nbkt] = E;
}

// P1c: bin edges into bucket-contiguous runs (block reserves per-bucket ranges)
__global__ __launch_bounds__(256) void bin_scatter_kernel(const int* __restrict__ src,
                                                          const int* __restrict__ dst,
                                                          int* __restrict__ bkt_cursor,
                                                          int2* __restrict__ ebuf,
                                                          int E, int nbkt) {
  __shared__ int hist[128];
  __shared__ int bbase[128];
  const int tid = threadIdx.x;
  if (tid < nbkt) hist[tid] = 0;
  __syncthreads();
  const int base = blockIdx.x * CHUNK;
  const int end = min(base + CHUNK, E);
  for (int e = base + tid; e < end; e += 256)
    atomicAdd(&hist[dst[e] >> BKT_SHIFT], 1);
  __syncthreads();
  if (tid < nbkt) {
    int c = hist[tid];
    bbase[tid] = c > 0 ? atomicAdd(&bkt_cursor[tid], c) : 0;
    hist[tid] = 0;  // reuse as intra-block cursor
  }
  __syncthreads();
  for (int e = base + tid; e < end; e += 256) {
    int d = dst[e];
    int b = d >> BKT_SHIFT;
    int off = atomicAdd(&hist[b], 1);
    ebuf[bbase[b] + off] = make_int2(src[e], d);
  }
}

// P2: per-bucket counting sort -> csr_src; emits row_start + dinv (degree for free)
__global__ __launch_bounds__(256) void bucket_sort_kernel(const int2* __restrict__ ebuf,
                                                          const int* __restrict__ bkt_start,
                                                          int* __restrict__ row_start,
                                                          float* __restrict__ dinv,
                                                          int* __restrict__ csr_src,
                                                          int N, int nbkt) {
  __shared__ int hist[BKT_SIZE];
  __shared__ int excl[BKT_SIZE];
  __shared__ int wsums[4];
  const int b = blockIdx.x;
  const int tid = threadIdx.x;
  const int node0 = b << BKT_SHIFT;
  const int nloc = min(BKT_SIZE, N - node0);
  const int ebeg = bkt_start[b], eend = bkt_start[b + 1];

  hist[tid] = 0; hist[tid + 256] = 0;
  __syncthreads();
  for (int e = ebeg + tid; e < eend; e += 256)
    atomicAdd(&hist[ebuf[e].y - node0], 1);
  __syncthreads();

  // 512-wide exclusive scan (2 elements / thread)
  const int h0 = hist[2 * tid], h1 = hist[2 * tid + 1];
  const int s = h0 + h1;
  const int lane = tid & 63, wid = tid >> 6;
  int incl = s;
#pragma unroll
  for (int off = 1; off < 64; off <<= 1) {
    int t = __shfl_up(incl, off);
    if (lane >= off) incl += t;
  }
  if (lane == 63) wsums[wid] = incl;
  __syncthreads();
  int wex = 0;
  for (int w = 0; w < wid; ++w) wex += wsums[w];
  const int ex = wex + incl - s;
  excl[2 * tid] = ex;
  excl[2 * tid + 1] = ex + h0;
  if (2 * tid < nloc) {
    row_start[node0 + 2 * tid] = ebeg + ex;
    dinv[node0 + 2 * tid] = rsqrtf((float)(h0 + 1));
  }
  if (2 * tid + 1 < nloc) {
    row_start[node0 + 2 * tid + 1] = ebeg + ex + h0;
    dinv[node0 + 2 * tid + 1] = rsqrtf((float)(h1 + 1));
  }
  if (b == nbkt - 1 && tid == 0) row_start[N] = eend;
  hist[2 * tid] = 0; hist[2 * tid + 1] = 0;  // reuse as per-node cursor
  __syncthreads();

  for (int e = ebeg + tid; e < eend; e += 256) {
    int2 ed = ebuf[e];
    int l = ed.y - node0;
    int pos = atomicAdd(&hist[l], 1);
    csr_src[ebeg + excl[l] + pos] = ed.x;
  }
}

// ================= conversions =================

__global__ void cvt_x_kernel(const float4* __restrict__ in, unsigned short* __restrict__ out,
                             int n4) {
  int i = blockIdx.x * 256 + threadIdx.x;
  if (i >= n4) return;
  float4 v = in[i];
  ushort4 o;
  o.x = f2b(v.x); o.y = f2b(v.y); o.z = f2b(v.z); o.w = f2b(v.w);
  *(ushort4*)(out + (size_t)i * 4) = o;
}

// W[K][N] fp32 -> Wt[N][K] bf16
__global__ void cvt_wt_kernel(const float* __restrict__ W, unsigned short* __restrict__ Wt,
                              int K, int N) {
  int e = blockIdx.x * 256 + threadIdx.x;
  if (e >= K * N) return;
  int k = e / N, n = e - k * N;
  Wt[(size_t)n * K + k] = f2b(W[e]);
}

// ================= MFMA bf16 GEMM: H[M][N_COLS] = A[M][K] @ Wt[N_COLS][K]^T =================
// 256 thr = 4 waves; block tile 64(M) x 64(N); each wave: 16 rows x 64 cols = 4 C-tiles.
// Layouts (verified m89/m91): A[m=lane&15][k=quad*8+j]; B[k=quad*8+j][n=lane&15];
// C/D: row=quad*4+reg, col=lane&15.

template<int N_COLS, int K, bool BIAS_RELU>
__global__ __launch_bounds__(256) void mfma_gemm_kernel(const unsigned short* __restrict__ A,
                                                        const unsigned short* __restrict__ Wt,
                                                        const float* __restrict__ bias,
                                                        unsigned short* __restrict__ H, int M) {
  const int tid = threadIdx.x;
  const int wave = tid >> 6;
  const int lane = tid & 63;
  const int quad = lane >> 4;
  const int l16 = lane & 15;
  const int row0 = blockIdx.x * 64 + wave * 16;
  const int col0 = blockIdx.y * 64;

  int arow = row0 + l16;
  if (arow >= M) arow = M - 1;  // tail: loads clamped, stores guarded
  const short8* ap = (const short8*)(A + (size_t)arow * K + quad * 8);
  const short8* bp = (const short8*)(Wt + (size_t)(col0 + l16) * K + quad * 8);
  constexpr int BSTEP = 2 * K;  // 16 rows of Wt in short8 units

  floatx4 acc0 = {0.f, 0.f, 0.f, 0.f}, acc1 = acc0, acc2 = acc0, acc3 = acc0;
#pragma unroll
  for (int kt = 0; kt < K / 32; ++kt) {
    short8 a  = ap[kt * 4];
    short8 b0 = bp[kt * 4];
    short8 b1 = bp[kt * 4 + BSTEP];
    short8 b2 = bp[kt * 4 + 2 * BSTEP];
    short8 b3 = bp[kt * 4 + 3 * BSTEP];
    acc0 = __builtin_amdgcn_mfma_f32_16x16x32_bf16(a, b0, acc0, 0, 0, 0);
    acc1 = __builtin_amdgcn_mfma_f32_16x16x32_bf16(a, b1, acc1, 0, 0, 0);
    acc2 = __builtin_amdgcn_mfma_f32_16x16x32_bf16(a, b2, acc2, 0, 0, 0);
    acc3 = __builtin_amdgcn_mfma_f32_16x16x32_bf16(a, b3, acc3, 0, 0, 0);
  }

  floatx4 accs[4] = {acc0, acc1, acc2, acc3};
#pragma unroll
  for (int t = 0; t < 4; ++t) {
    const int col = col0 + t * 16 + l16;
    const float bv = BIAS_RELU ? bias[col] : 0.f;
#pragma unroll
    for (int r = 0; r < 4; ++r) {
      const int row = row0 + quad * 4 + r;
      if (row < M) {
        float v = accs[t][r];
        if (BIAS_RELU) { v += bv; v = v > 0.f ? v : 0.f; }
        H[(size_t)row * N_COLS + col] = f2b(v);
      }
    }
  }
}

// ================= CSR aggregation over bf16 rows (D=128), fp32 accumulate =================
// 16 lanes/node (8 dims each, one uint4 = 8 bf16 per gather), 16 nodes / 256-thr block.

template<bool SKIP_BIAS>
__global__ __launch_bounds__(256) void agg_kernel(const uint4* __restrict__ Hq,  // bf16 [n][128]
                                                  const int* __restrict__ row_start,
                                                  const int* __restrict__ csr_src,
                                                  const float* __restrict__ dinv,
                                                  const float* __restrict__ skip,
                                                  const float* __restrict__ bias,
                                                  void* __restrict__ OUT, int n) {
  const int lane = threadIdx.x & 15;
  const int node = blockIdx.x * 16 + (threadIdx.x >> 4);
  if (node >= n) return;

  const float dv = dinv[node];
  float f[8], acc[8];
  uint4 sv = Hq[(size_t)node * 16 + lane];
  unpack8(sv, f);
  const float wself = dv * dv;
#pragma unroll
  for (int d = 0; d < 8; ++d) acc[d] = f[d] * wself;

  int j = row_start[node];
  const int end = row_start[node + 1];
  for (; j + 4 <= end; j += 4) {
    int s0 = csr_src[j], s1 = csr_src[j + 1], s2 = csr_src[j + 2], s3 = csr_src[j + 3];
    float w0 = dinv[s0] * dv, w1 = dinv[s1] * dv, w2 = dinv[s2] * dv, w3 = dinv[s3] * dv;
    uint4 v0 = Hq[(size_t)s0 * 16 + lane];
    uint4 v1 = Hq[(size_t)s1 * 16 + lane];
    uint4 v2 = Hq[(size_t)s2 * 16 + lane];
    uint4 v3 = Hq[(size_t)s3 * 16 + lane];
    float g[8];
    unpack8(v0, g);
#pragma unroll
    for (int d = 0; d < 8; ++d) acc[d] = fmaf(g[d], w0, acc[d]);
    unpack8(v1, g);
#pragma unroll
    for (int d = 0; d < 8; ++d) acc[d] = fmaf(g[d], w1, acc[d]);
    unpack8(v2, g);
#pragma unroll
    for (int d = 0; d < 8; ++d) acc[d] = fmaf(g[d], w2, acc[d]);
    unpack8(v3, g);
#pragma unroll
    for (int d = 0; d < 8; ++d) acc[d] = fmaf(g[d], w3, acc[d]);
  }
  for (; j < end; ++j) {
    int s0 = csr_src[j];
    float w0 = dinv[s0] * dv;
    uint4 v0 = Hq[(size_t)s0 * 16 + lane];
    float g[8];
    unpack8(v0, g);
#pragma unroll
    for (int d = 0; d < 8; ++d) acc[d] = fmaf(g[d], w0, acc[d]);
  }

  if (SKIP_BIAS) {
    const float* sp = skip + (size_t)node * 128 + lane * 8;
    const float* bp = bias + lane * 8;
    float4 s0 = *(const float4*)sp, s1 = *(const float4*)(sp + 4);
    float4 b0 = *(const float4*)bp, b1 = *(const float4*)(bp + 4);
    float* op = (float*)OUT + (size_t)node * 128 + lane * 8;
    float4 o0 = make_float4(acc[0] + s0.x + b0.x, acc[1] + s0.y + b0.y,
                            acc[2] + s0.z + b0.z, acc[3] + s0.w + b0.w);
    float4 o1 = make_float4(acc[4] + s1.x + b1.x, acc[5] + s1.y + b1.y,
                            acc[6] + s1.z + b1.z, acc[7] + s1.w + b1.w);
    *(float4*)op = o0;
    *(float4*)(op + 4) = o1;
  } else {
    uint4 o;
    o.x = (unsigned)f2b(acc[0]) | ((unsigned)f2b(acc[1]) << 16);
    o.y = (unsigned)f2b(acc[2]) | ((unsigned)f2b(acc[3]) << 16);
    o.z = (unsigned)f2b(acc[4]) | ((unsigned)f2b(acc[5]) << 16);
    o.w = (unsigned)f2b(acc[6]) | ((unsigned)f2b(acc[7]) << 16);
    ((uint4*)OUT)[(size_t)node * 16 + lane] = o;
  }
}

// ================= launch =================

extern "C" void kernel_launch(void* const* d_in, const int* in_sizes, int n_in,
                              void* d_out, int out_size, void* d_ws, size_t ws_size,
                              hipStream_t stream) {
  const float* x  = (const float*)d_in[0];
  const int*   ei = (const int*)d_in[1];
  const float* W1 = (const float*)d_in[2];
  const float* b1 = (const float*)d_in[3];
  const float* W2 = (const float*)d_in[4];
  const float* b2 = (const float*)d_in[5];
  float* out = (float*)d_out;

  const int N = in_sizes[0] / D_IN;
  const int E = in_sizes[1] / 2;
  const int* srcA = ei;
  const int* dstA = ei + E;
  const int NBKT = (N + BKT_SIZE - 1) >> BKT_SHIFT;     // 98 for N=50000 (<=128 req)
  const int NCHUNK = (E + CHUNK - 1) / CHUNK;           // 196 for E=1.6M

  // ---- workspace (256B aligned) ----
  char* ws = (char*)d_ws;
  size_t off = 0;
  auto alloc = [&](size_t bytes) { void* p = ws + off; off = (off + bytes + 255) & ~(size_t)255; return p; };
  int*            bkt_cnt    = (int*)           alloc((size_t)NBKT * 4);
  int*            bkt_start  = (int*)           alloc((size_t)(NBKT + 1) * 4);
  int*            bkt_cursor = (int*)           alloc((size_t)NBKT * 4);
  int*            row_start  = (int*)           alloc((size_t)(N + 1) * 4);
  float*          dinv       = (float*)         alloc((size_t)N * 4);
  int2*           ebuf       = (int2*)          alloc((size_t)E * 8);
  int*            csr_src    = (int*)           alloc((size_t)E * 4);
  unsigned short* xb         = (unsigned short*)alloc((size_t)N * D_IN * 2);
  unsigned short* aggx       = (unsigned short*)alloc((size_t)N * D_IN * 2);
  unsigned short* h          = (unsigned short*)alloc((size_t)N * HID * 2);
  unsigned short* tb         = (unsigned short*)alloc((size_t)N * D_IN * 2);
  unsigned short* Wt1        = (unsigned short*)alloc((size_t)D_IN * HID * 2);
  unsigned short* Wt2        = (unsigned short*)alloc((size_t)D_IN * HID * 2);

  // 1) CSR build via two-level binning (also emits row_start + dinv)
  hipMemsetAsync(bkt_cnt, 0, (size_t)NBKT * 4, stream);
  bin_hist_kernel<<<NCHUNK, 256, 0, stream>>>(dstA, bkt_cnt, E, NBKT);
  bkt_scan_kernel<<<1, 128, 0, stream>>>(bkt_cnt, bkt_start, bkt_cursor, NBKT, E);
  bin_scatter_kernel<<<NCHUNK, 256, 0, stream>>>(srcA, dstA, bkt_cursor, ebuf, E, NBKT);
  bucket_sort_kernel<<<NBKT, 256, 0, stream>>>(ebuf, bkt_start, row_start, dinv, csr_src, N, NBKT);

  // 2) conversions
  cvt_x_kernel<<<(N * D_IN / 4 + 255) / 256, 256, 0, stream>>>((const float4*)x, xb, N * D_IN / 4);
  cvt_wt_kernel<<<(D_IN * HID + 255) / 256, 256, 0, stream>>>(W1, Wt1, D_IN, HID);
  cvt_wt_kernel<<<(D_IN * HID + 255) / 256, 256, 0, stream>>>(W2, Wt2, HID, D_IN);

  // 3) aggx = Â x   (bf16 in/out)
  agg_kernel<false><<<(N + 15) / 16, 256, 0, stream>>>((const uint4*)xb, row_start, csr_src,
                                                       dinv, nullptr, nullptr, aggx, N);
  // 4) h = relu(aggx @ W1 + b1)
  {
    dim3 g((N + 63) / 64, HID / 64);
    mfma_gemm_kernel<HID, D_IN, true><<<g, 256, 0, stream>>>(aggx, Wt1, b1, h, N);
  }
  // 5) t = h @ W2
  {
    dim3 g((N + 63) / 64, D_IN / 64);
    mfma_gemm_kernel<D_IN, HID, false><<<g, 256, 0, stream>>>(h, Wt2, nullptr, tb, N);
  }
  // 6) out = Â t + x + b2  (fp32 out)
  agg_kernel<true><<<(N + 15) / 16, 256, 0, stream>>>((const uint4*)tb, row_start, csr_src,
                                                      dinv, x, b2, out, N);
}